// Round 11
// baseline (25.311 us; speedup 1.0000x reference)
//
#include <hip/hip_runtime.h>

// RBF network, single fused kernel — 2-blocks/CU experiment.
// Block: 4 rows x all 512 h, 512 thr, LDS ~50 KB, grid 512 => 2 blocks/CU
// (independent blocks overlap each other's barrier drains / load latency).
// Main loop: lane owns h = wave*64+lane (c b32, conflict-free), x broadcast b128
// of rows 0..3, acc[4]. Staging: KC=16 reg-prefetch, write-late. dist = xn+cn-2dot.
// inputs:  x[B=2048][F=128], centers c[H=512][F=128], sigma[1], W[O=10][H=512], b[O=10]

constexpr int Fdim = 128;
constexpr int Hdim = 512;
constexpr int Odim = 10;
constexpr int BM   = 4;          // rows per block
constexpr int KC   = 16;         // F chunk resident in LDS
constexpr int NCH  = Fdim / KC;  // 8
constexpr int LDC  = 513;        // cT row stride
constexpr int LDXT = 8;          // xT row stride (32B rows, b128-aligned)
constexpr int LDR  = 516;        // rbf_s row stride

__global__ __launch_bounds__(512, 4) void rbf_all(
    const float* __restrict__ x,
    const float* __restrict__ c,
    const float* __restrict__ sigmap,
    const float* __restrict__ W,
    const float* __restrict__ bias,
    float* __restrict__ out)
{
    __shared__ float cT[KC][LDC];         // 32.8 KB  current c chunk, f-major
    __shared__ float xT[Fdim][LDXT];      //  4.0 KB  x rows 0..3, f-major
    __shared__ float rbf_s[BM][LDR];      //  8.3 KB
    __shared__ float po_s[BM][16][Odim];  //  2.6 KB
    __shared__ float xn_s[BM];
    __shared__ float cn_s[Hdim];          // ~49.9 KB total -> 3 blocks/CU by LDS

    const int tid  = threadIdx.x;
    const int lane = tid & 63;
    const int wave = tid >> 6;          // 0..7
    const int row0 = blockIdx.x * BM;

    const float4* x4 = reinterpret_cast<const float4*>(x);
    const float4* c4 = reinterpret_cast<const float4*>(c);

    // ---- c staging state: sfq = f-quad within chunk (4), h = sh + 128p
    const int sfq = tid & 3;
    const int sh  = tid >> 2;    // 0..127

    float4 pre[4];
    float cnp[4] = {0.0f, 0.0f, 0.0f, 0.0f};

#define CLOAD(k)                                                               \
    {                                                                          \
        _Pragma("unroll")                                                      \
        for (int p = 0; p < 4; ++p)                                            \
            pre[p] = c4[(size_t)(sh + 128 * p) * (Fdim / 4) + (k) * 4 + sfq];  \
    }
#define CWRITE(k)                                                              \
    {                                                                          \
        _Pragma("unroll")                                                      \
        for (int p = 0; p < 4; ++p) {                                          \
            float4 v = pre[p];                                                 \
            int h = sh + 128 * p;                                              \
            cT[4 * sfq + 0][h] = v.x;                                          \
            cT[4 * sfq + 1][h] = v.y;                                          \
            cT[4 * sfq + 2][h] = v.z;                                          \
            cT[4 * sfq + 3][h] = v.w;                                          \
            cnp[p] += v.x * v.x + v.y * v.y + v.z * v.z + v.w * v.w;           \
        }                                                                      \
    }

    CLOAD(0);   // issue earliest

    // ---- stage x rows 0..3 transposed + row norms (hides chunk0 load latency)
    if (tid < 128) {
        int r  = tid >> 5;    // 0..3
        int fq = tid & 31;
        float4 v = x4[(size_t)(row0 + r) * (Fdim / 4) + fq];
        xT[4 * fq + 0][r] = v.x;
        xT[4 * fq + 1][r] = v.y;
        xT[4 * fq + 2][r] = v.z;
        xT[4 * fq + 3][r] = v.w;
        float s = v.x * v.x + v.y * v.y + v.z * v.z + v.w * v.w;
#pragma unroll
        for (int sft = 1; sft < 32; sft <<= 1) s += __shfl_xor(s, sft, 64);
        if (fq == 0) xn_s[r] = s;
    }

    CWRITE(0);
    CLOAD(1);
    __syncthreads();   // cT chunk0 + xT + xn visible

    float acc[4] = {0.0f, 0.0f, 0.0f, 0.0f};
    const int hown = wave * 64 + lane;   // this thread's h

    for (int k = 0; k < NCH; ++k) {
        // ---- compute chunk k (CLOAD(k+1) latency hides under these FMAs)
#pragma unroll
        for (int f = 0; f < KC; ++f) {
            float4 xv = *reinterpret_cast<const float4*>(&xT[k * KC + f][0]);
            float  cv = cT[f][hown];
            acc[0] = fmaf(xv.x, cv, acc[0]);
            acc[1] = fmaf(xv.y, cv, acc[1]);
            acc[2] = fmaf(xv.z, cv, acc[2]);
            acc[3] = fmaf(xv.w, cv, acc[3]);
        }
        if (k + 1 < NCH) {
            __syncthreads();          // all readers done with chunk k
            CWRITE(k + 1);
            if (k + 2 < NCH) CLOAD(k + 2);
            __syncthreads();          // chunk k+1 visible
        }
    }
#undef CLOAD
#undef CWRITE

    // ---- W into registers (this wave's row/h-half slice; hides under norms/exp)
    const int erow  = wave & 3;     // epilogue row
    const int ehalf = wave >> 2;    // h-half (256 h)
    float2 W2[Odim][2];
#pragma unroll
    for (int o = 0; o < Odim; ++o)
#pragma unroll
        for (int kk = 0; kk < 2; ++kk)
            W2[o][kk] = *reinterpret_cast<const float2*>(
                &W[o * Hdim + ehalf * 256 + 2 * lane + 128 * kk]);

    // ---- center norms: reduce over 4 sfq-lanes, publish
#pragma unroll
    for (int p = 0; p < 4; ++p) {
        float s = cnp[p];
        s += __shfl_xor(s, 1, 64);
        s += __shfl_xor(s, 2, 64);
        cnp[p] = s;
    }
    if (sfq == 0) {
#pragma unroll
        for (int p = 0; p < 4; ++p) cn_s[sh + 128 * p] = cnp[p];
    }
    __syncthreads();

    // ---- rbf = exp(dist*scale): thread owns column hown
    const float sg    = sigmap[0];
    const float scale = -1.0f / (2.0f * sg * sg);
    {
        float cn = cn_s[hown];
#pragma unroll
        for (int r = 0; r < 4; ++r) {
            float d = xn_s[r] + cn - 2.0f * acc[r];
            rbf_s[r][hown] = __expf(d * scale);
        }
    }
    __syncthreads();

    // ---- epilogue: wave -> (row, h-half); W from regs; 3-step butterfly
    {
        float po[Odim];
#pragma unroll
        for (int o = 0; o < Odim; ++o) po[o] = 0.0f;

#pragma unroll
        for (int kk = 0; kk < 2; ++kk) {
            float2 rv = *reinterpret_cast<const float2*>(
                &rbf_s[erow][ehalf * 256 + 2 * lane + 128 * kk]);
#pragma unroll
            for (int o = 0; o < Odim; ++o) {
                po[o] = fmaf(rv.x, W2[o][kk].x, po[o]);
                po[o] = fmaf(rv.y, W2[o][kk].y, po[o]);
            }
        }
#pragma unroll
        for (int s = 1; s < 8; s <<= 1) {
#pragma unroll
            for (int o = 0; o < Odim; ++o)
                po[o] += __shfl_xor(po[o], s, 64);
        }
        if ((lane & 7) == 0) {
#pragma unroll
            for (int o = 0; o < Odim; ++o)
                po_s[erow][ehalf * 8 + (lane >> 3)][o] = po[o];
        }
    }
    __syncthreads();

    // ---- finish: 40 threads, one (row,o) each
    if (tid < BM * Odim) {
        int w = tid / Odim;
        int o = tid - w * Odim;
        float v = bias[o];
#pragma unroll
        for (int g = 0; g < 16; ++g) v += po_s[w][g][o];
        out[(size_t)(row0 + w) * Odim + o] = v;
    }
}

extern "C" void kernel_launch(void* const* d_in, const int* in_sizes, int n_in,
                              void* d_out, int out_size, void* d_ws, size_t ws_size,
                              hipStream_t stream) {
    const float* x  = (const float*)d_in[0];
    const float* c  = (const float*)d_in[1];
    const float* sg = (const float*)d_in[2];
    const float* W  = (const float*)d_in[3];
    const float* b  = (const float*)d_in[4];
    float* out      = (float*)d_out;

    const int B = in_sizes[0] / Fdim;   // 2048

    rbf_all<<<B / BM, 512, 0, stream>>>(x, c, sg, W, b, out);
}

// Round 12
// 17.666 us; speedup vs baseline: 1.4328x; 1.4328x over previous
//
#include <hip/hip_runtime.h>

// RBF network, single fused kernel, reg-prefetch double-buffered c staging (T14).
// BEST-MEASURED CONFIGURATION (17.64 us, Round 5) — resubmitted verbatim after
// R6-R10 ablations all came back null or negative:
//   - one graph node (nodes cost ~1-3 us each: R2->R3->R4)
//   - write-late reg-prefetch staging (exposed-latency fix: R4->R5 -1.03 us)
//   - 8 rows x all-512-h block, broadcast-x b128 + contiguous-c b64 main loop
//   - measured-worse alternatives: scalar-x (+8.4), KC16 dbuf (+2.9/+1.5),
//     W-reg epilogue (+0.24), f-split waves (+1.1), 2 blocks/CU (+7.7)
// inputs:  x[B=2048][F=128], centers c[H=512][F=128], sigma[1], W[O=10][H=512], b[O=10]
// dist = |x|^2+|c|^2-2x.c ; plain store, no atomics.

constexpr int Fdim = 128;
constexpr int Hdim = 512;
constexpr int Odim = 10;
constexpr int BM   = 8;          // rows per block
constexpr int KC   = 32;         // F chunk resident in LDS
constexpr int NCH  = Fdim / KC;  // 4
constexpr int LDC  = 513;        // cT row stride (2-way-free writes, conflict-free b64 reads)
constexpr int LDXT = 12;         // xT row stride (48B rows, b128-aligned at 4*wr)
constexpr int LDR  = 516;        // rbf_s row stride

__global__ __launch_bounds__(512, 1) void rbf_all(
    const float* __restrict__ x,
    const float* __restrict__ c,
    const float* __restrict__ sigmap,
    const float* __restrict__ W,
    const float* __restrict__ bias,
    float* __restrict__ out)
{
    __shared__ float cT[KC][LDC];        // 65.7 KB  current c chunk, f-major
    __shared__ float xT[Fdim][LDXT];     //  6.1 KB  all x rows, f-major (staged once)
    __shared__ float W_s[Odim][Hdim];    // 20.5 KB
    __shared__ float rbf_s[BM][LDR];     // 16.5 KB
    __shared__ float xn_s[BM];
    __shared__ float cn_s[Hdim];         // total ~111 KB -> 1 block/CU (grid=256 anyway)

    const int tid  = threadIdx.x;
    const int lane = tid & 63;
    const int wave = tid >> 6;          // 0..7
    const int wr   = wave >> 2;         // rows 4wr..4wr+3
    const int wh   = wave & 3;          // h in [wh*128, wh*128+128)
    const int row0 = blockIdx.x * BM;

    const float4* x4 = reinterpret_cast<const float4*>(x);
    const float4* c4 = reinterpret_cast<const float4*>(c);

    // ---- stage W (once): flat copy
#pragma unroll
    for (int k = 0; k < (Odim * Hdim) / 512; ++k) {   // 10
        int idx = tid + 512 * k;
        W_s[idx >> 9][idx & 511] = W[idx];
    }

    // ---- stage ALL x, transposed (once), + row norms
    if (tid < 256) {
        int r  = tid >> 5;    // 0..7
        int fq = tid & 31;    // float4 index along f
        float4 v = x4[(size_t)(row0 + r) * (Fdim / 4) + fq];
        xT[4 * fq + 0][r] = v.x;
        xT[4 * fq + 1][r] = v.y;
        xT[4 * fq + 2][r] = v.z;
        xT[4 * fq + 3][r] = v.w;
        float s = v.x * v.x + v.y * v.y + v.z * v.z + v.w * v.w;
#pragma unroll
        for (int sft = 1; sft < 32; sft <<= 1) s += __shfl_xor(s, sft, 64);
        if (fq == 0) xn_s[r] = s;
    }

    // ---- c staging: reg-prefetch double buffer
    const int f4 = tid & 7;     // f-quad within chunk
    const int hh = tid >> 3;    // 0..63

    float4 pre[8];
    float cn_part[8];
#pragma unroll
    for (int p = 0; p < 8; ++p) cn_part[p] = 0.0f;

    // prologue: load chunk 0 into regs, write to LDS
#pragma unroll
    for (int p = 0; p < 8; ++p)
        pre[p] = c4[(size_t)(hh + 64 * p) * (Fdim / 4) + f4];
#pragma unroll
    for (int p = 0; p < 8; ++p) {
        float4 v = pre[p];
        int h = hh + 64 * p;
        cT[4 * f4 + 0][h] = v.x;
        cT[4 * f4 + 1][h] = v.y;
        cT[4 * f4 + 2][h] = v.z;
        cT[4 * f4 + 3][h] = v.w;
        cn_part[p] += v.x * v.x + v.y * v.y + v.z * v.z + v.w * v.w;
    }
    __syncthreads();   // cT chunk0 + xT + W_s visible

    float acc[4][2];
#pragma unroll
    for (int i = 0; i < 4; ++i) { acc[i][0] = 0.0f; acc[i][1] = 0.0f; }

    for (int k = 0; k < NCH; ++k) {
        // issue next chunk's global loads (latency hides under compute below)
        if (k + 1 < NCH) {
#pragma unroll
            for (int p = 0; p < 8; ++p)
                pre[p] = c4[(size_t)(hh + 64 * p) * (Fdim / 4) + (k + 1) * (KC / 4) + f4];
        }

        // ---- compute chunk k: x read wave-uniform b128 (broadcast), c read b64 contiguous
#pragma unroll 8
        for (int f = 0; f < KC; ++f) {
            float4 xv = *reinterpret_cast<const float4*>(&xT[k * KC + f][4 * wr]);
            float2 cv = *reinterpret_cast<const float2*>(&cT[f][wh * 128 + 2 * lane]);
            acc[0][0] = fmaf(xv.x, cv.x, acc[0][0]);
            acc[0][1] = fmaf(xv.x, cv.y, acc[0][1]);
            acc[1][0] = fmaf(xv.y, cv.x, acc[1][0]);
            acc[1][1] = fmaf(xv.y, cv.y, acc[1][1]);
            acc[2][0] = fmaf(xv.z, cv.x, acc[2][0]);
            acc[2][1] = fmaf(xv.z, cv.y, acc[2][1]);
            acc[3][0] = fmaf(xv.w, cv.x, acc[3][0]);
            acc[3][1] = fmaf(xv.w, cv.y, acc[3][1]);
        }

        if (k + 1 < NCH) {
            __syncthreads();   // everyone done reading cT chunk k
#pragma unroll
            for (int p = 0; p < 8; ++p) {
                float4 v = pre[p];
                int h = hh + 64 * p;
                cT[4 * f4 + 0][h] = v.x;
                cT[4 * f4 + 1][h] = v.y;
                cT[4 * f4 + 2][h] = v.z;
                cT[4 * f4 + 3][h] = v.w;
                cn_part[p] += v.x * v.x + v.y * v.y + v.z * v.z + v.w * v.w;
            }
            __syncthreads();   // chunk k+1 visible
        }
    }

    // ---- publish center norms (reduce over the 8 f4-lanes)
#pragma unroll
    for (int p = 0; p < 8; ++p) {
        float s = cn_part[p];
        s += __shfl_xor(s, 1, 64);
        s += __shfl_xor(s, 2, 64);
        s += __shfl_xor(s, 4, 64);
        cn_part[p] = s;
    }
    if (f4 == 0) {
#pragma unroll
        for (int p = 0; p < 8; ++p) cn_s[hh + 64 * p] = cn_part[p];
    }
    __syncthreads();

    // ---- rbf = exp(dist*scale) -> rbf_s
    const float sg    = sigmap[0];
    const float scale = -1.0f / (2.0f * sg * sg);
    {
        float2 cn = *reinterpret_cast<const float2*>(&cn_s[wh * 128 + 2 * lane]);
#pragma unroll
        for (int i = 0; i < 4; ++i) {
            float xn = xn_s[4 * wr + i];
            float2 rv;
            rv.x = __expf((xn + cn.x - 2.0f * acc[i][0]) * scale);
            rv.y = __expf((xn + cn.y - 2.0f * acc[i][1]) * scale);
            *reinterpret_cast<float2*>(&rbf_s[4 * wr + i][wh * 128 + 2 * lane]) = rv;
        }
    }
    __syncthreads();

    // ---- GEMV epilogue: wave = row, lane h-mapping contiguous (conflict-free)
    {
        const int row = wave;   // 0..7
        float po[Odim];
#pragma unroll
        for (int o = 0; o < Odim; ++o) po[o] = 0.0f;

#pragma unroll
        for (int k = 0; k < 8; ++k) {
            int h = lane + 64 * k;
            float r = rbf_s[row][h];
#pragma unroll
            for (int o = 0; o < Odim; ++o)
                po[o] = fmaf(r, W_s[o][h], po[o]);
        }
#pragma unroll
        for (int s = 1; s < 64; s <<= 1) {
#pragma unroll
            for (int o = 0; o < Odim; ++o)
                po[o] += __shfl_xor(po[o], s, 64);
        }
        if (lane == 0) {
#pragma unroll
            for (int o = 0; o < Odim; ++o)
                out[(size_t)(row0 + row) * Odim + o] = po[o] + bias[o];
        }
    }
}

extern "C" void kernel_launch(void* const* d_in, const int* in_sizes, int n_in,
                              void* d_out, int out_size, void* d_ws, size_t ws_size,
                              hipStream_t stream) {
    const float* x  = (const float*)d_in[0];
    const float* c  = (const float*)d_in[1];
    const float* sg = (const float*)d_in[2];
    const float* W  = (const float*)d_in[3];
    const float* b  = (const float*)d_in[4];
    float* out      = (float*)d_out;

    const int B = in_sizes[0] / Fdim;   // 2048

    rbf_all<<<B / BM, 512, 0, stream>>>(x, c, sg, W, b, out);
}